// Round 5
// baseline (2114.876 us; speedup 1.0000x reference)
//
#include <hip/hip_runtime.h>
#include <hip/hip_cooperative_groups.h>
#include <math.h>

namespace cg = cooperative_groups;

#define S_ROWS 2047
#define DIM 256
#define HID 512
#define NHEADS 8
#define DH 32
#define NBINS 16
#define AFF_OUT 49

typedef short bf16x8 __attribute__((ext_vector_type(8)));
typedef float f32x4 __attribute__((ext_vector_type(4)));
typedef float f32x16 __attribute__((ext_vector_type(16)));
typedef unsigned short u16x8 __attribute__((ext_vector_type(8)));
typedef unsigned short u16x4 __attribute__((ext_vector_type(4)));

__device__ inline unsigned short f2b(float f) {
    unsigned int u = __float_as_uint(f);
    u += 0x7FFFu + ((u >> 16) & 1u);      // round-to-nearest-even
    return (unsigned short)(u >> 16);
}

// bf16 weight region offsets (u16 elements): [ew0p | main segments]
#define OFF_EW0 0
#define OFF_EW1 (32768 + 0)
#define OFF_EW2 (32768 + 262144)
#define OFF_WQ  (32768 + 393216)
#define OFF_WK  (32768 + 655360)
#define OFF_WV  (32768 + 917504)
#define OFF_WO  (32768 + 1179648)
#define OFF_MW0 (32768 + 1441792)
#define OFF_MW1 (32768 + 1966080)
#define OFF_MW2 (32768 + 3014656)
#define OFF_AW0 (32768 + 3538944)
#define OFF_AW1 (32768 + 3670016)
#define OFF_AW2 (32768 + 3932160)

#define W_MAIN 3957248
#define EW0P_N 32768
#define P0 (W_MAIN / 4)                   // main weights (4 elems per i4)
#define P1 (P0 + EW0P_N / 4)              // ew0 padded
#define P2 (P1 + 2048 * 64 / 4)           // cond features
#define P3 (P2 + 1537)                    // pos copy (6148/4)

// ---------------------------------------------------------------------------
// Setup body (verified): weight f32->bf16 (+ew0 pad), circular features,
// pos copy + out[6144]=0. Grid-stride over flat i4 index.
// ---------------------------------------------------------------------------
__device__ __forceinline__ void setup_body(
    int tid0, int tstride,
    const float* pos, const float* scale, const float* press, const float* temp,
    const float* e_w0,
    const float* p0, const float* p1, const float* p2, const float* p3,
    const float* p4, const float* p5, const float* p6, const float* p7,
    const float* p8, const float* p9, const float* p10, const float* p11,
    unsigned short* dst, unsigned short* cond, float* out)
{
    const int offs[13] = {0, 262144, 393216, 655360, 917504, 1179648, 1441792,
                          1966080, 3014656, 3538944, 3670016, 3932160, 3957248};
    const float* srcs[12] = {p0,p1,p2,p3,p4,p5,p6,p7,p8,p9,p10,p11};
    for (int i4 = tid0; i4 < P3; i4 += tstride) {
        if (i4 < P0) {
            int e = i4 * 4;
            int s = 0;
            #pragma unroll
            for (int j = 1; j < 12; j++) s += (e >= offs[j]);
            const float4 v = *(const float4*)(srcs[s] + (e - offs[s]));
            u16x4 o;
            o[0] = f2b(v.x); o[1] = f2b(v.y); o[2] = f2b(v.z); o[3] = f2b(v.w);
            *(u16x4*)(dst + EW0P_N + e) = o;
        } else if (i4 < P1) {
            int e = (i4 - P0) * 4;
            u16x4 o;
            #pragma unroll
            for (int r = 0; r < 4; r++) {
                int ee = e + r;
                int row = ee >> 6, col = ee & 63;
                o[r] = (col < 35) ? f2b(e_w0[row * 35 + col]) : (unsigned short)0;
            }
            *(u16x4*)(dst + e) = o;
        } else if (i4 < P2) {
            int e = (i4 - P1) * 4;
            int row = e >> 6;
            u16x4 o;
            #pragma unroll
            for (int r = 0; r < 4; r++) {
                int c = (e + r) & 63;
                float v = 0.f;
                if (row < S_ROWS) {
                    if (c < 32) {
                        int coord = c >> 4;
                        int w = c & 15;
                        float x = pos[(row + 1) * 3 + coord];
                        float f = 6.283185307179586f * (float)((w & 7) + 1);
                        float ang = x * f;
                        v = (w < 8) ? cosf(ang) : sinf(ang);
                    } else if (c == 32) v = scale[0];
                    else if (c == 33) v = temp[0];
                    else if (c == 34) v = press[0];
                }
                o[r] = f2b(v);
            }
            *(u16x4*)(cond + e) = o;
        } else {
            int e = (i4 - P2) * 4;
            #pragma unroll
            for (int r = 0; r < 4; r++) {
                int ee = e + r;
                if (ee < 6144) out[ee] = pos[ee];
                else if (ee == 6144) out[ee] = 0.f;
            }
        }
    }
}

// ---------------------------------------------------------------------------
// One 32x32 GEMM tile, 4 waves (verified round-4 body).
// ---------------------------------------------------------------------------
#define LDK 72
__device__ __forceinline__ void gemm_tile_one(
    unsigned short (*As)[LDK], unsigned short (*Bs)[LDK],
    int row0, int col0,
    const unsigned short* __restrict__ Ab, const unsigned short* __restrict__ W,
    const float* __restrict__ bias, const float* resF,
    float* Cf, unsigned short* Cb, int M, int K, int relu)
{
    int tid = threadIdx.x;
    int wave = tid >> 6, lane = tid & 63;
    int quad = lane >> 4, l16 = lane & 15;
    int rowf = (wave & 1) << 4, colf = (wave >> 1) << 4;
    int srow = tid >> 3, scol = (tid & 7) << 3;      // 32 rows x 64 k stage

    f32x4 acc = {0.f, 0.f, 0.f, 0.f};

    const u16x8* ap = (const u16x8*)(Ab + (size_t)(row0 + srow) * K + scol);
    const u16x8* wp = (const u16x8*)(W + (size_t)(col0 + srow) * K + scol);
    u16x8 a0 = ap[0];
    u16x8 b0 = wp[0];

    for (int k0 = 0; k0 < K; k0 += 64) {
        *(u16x8*)&As[srow][scol] = a0;
        *(u16x8*)&Bs[srow][scol] = b0;
        __syncthreads();
        if (k0 + 64 < K) {               // prefetch next tile (stays in flight)
            ap += 8; wp += 8;
            a0 = ap[0]; b0 = wp[0];
        }
        #pragma unroll
        for (int kt = 0; kt < 64; kt += 32) {
            bf16x8 af = *(bf16x8*)&As[rowf + l16][kt + (quad << 3)];
            bf16x8 bf = *(bf16x8*)&Bs[colf + l16][kt + (quad << 3)];
            acc = __builtin_amdgcn_mfma_f32_16x16x32_bf16(af, bf, acc, 0, 0, 0);
        }
        __syncthreads();
    }
    int col = col0 + colf + l16;
    if (col < M) {
        float bv = bias ? bias[col] : 0.f;
        #pragma unroll
        for (int r = 0; r < 4; r++) {
            int row = row0 + rowf + (quad << 2) + r;
            if (row >= S_ROWS) continue;
            float v = acc[r] + bv;
            if (resF) v += resF[(size_t)row * M + col];
            if (relu) v = fmaxf(v, 0.f);
            if (Cf) Cf[(size_t)row * M + col] = v;
            if (Cb) Cb[(size_t)row * M + col] = f2b(v);
        }
    }
}

// ---------------------------------------------------------------------------
// One 32x32 QKV tile -> attention-native layouts (verified round-4 body).
// ---------------------------------------------------------------------------
__device__ __forceinline__ void qkv_tile_one(
    unsigned short (*As)[LDK], unsigned short (*Bs)[LDK],
    int row0, int col0,
    const unsigned short* __restrict__ Ab, const unsigned short* __restrict__ Wq,
    const unsigned short* __restrict__ Wk, const unsigned short* __restrict__ Wv,
    const float* __restrict__ bk,
    unsigned short* qbh, unsigned short* kbh, unsigned short* vbT)
{
    const int N = S_ROWS, K = 256;
    int tid = threadIdx.x;
    int wave = tid >> 6, lane = tid & 63;
    int quad = lane >> 4, l16 = lane & 15;
    int rowf = (wave & 1) << 4, colf = (wave >> 1) << 4;
    int mode = col0 >> 8;                 // 0=q 1=k 2=v
    int wcol0 = col0 & 255;
    const unsigned short* W = (mode == 0) ? Wq : (mode == 1) ? Wk : Wv;
    int srow = tid >> 3, scol = (tid & 7) << 3;

    f32x4 acc = {0.f, 0.f, 0.f, 0.f};

    const u16x8* ap = (const u16x8*)(Ab + (size_t)(row0 + srow) * K + scol);
    const u16x8* wp = (const u16x8*)(W + (size_t)(wcol0 + srow) * K + scol);
    u16x8 a0 = ap[0];
    u16x8 b0 = wp[0];

    for (int k0 = 0; k0 < K; k0 += 64) {
        *(u16x8*)&As[srow][scol] = a0;
        *(u16x8*)&Bs[srow][scol] = b0;
        __syncthreads();
        if (k0 + 64 < K) {
            ap += 8; wp += 8;
            a0 = ap[0]; b0 = wp[0];
        }
        #pragma unroll
        for (int kt = 0; kt < 64; kt += 32) {
            bf16x8 af = *(bf16x8*)&As[rowf + l16][kt + (quad << 3)];
            bf16x8 bf = *(bf16x8*)&Bs[colf + l16][kt + (quad << 3)];
            acc = __builtin_amdgcn_mfma_f32_16x16x32_bf16(af, bf, acc, 0, 0, 0);
        }
        __syncthreads();
    }
    int colr = wcol0 + colf + l16;        // 0..255
    int hh = colr >> 5, d = colr & 31;
    int rbase = row0 + rowf + (quad << 2);
    if (mode == 2) {
        unsigned short* dst = vbT + ((size_t)hh * 32 + d) * 2048 + rbase;
        if (rbase + 3 < N) {
            u16x4 o;
            #pragma unroll
            for (int r = 0; r < 4; r++) o[r] = f2b(acc[r]);
            *(u16x4*)dst = o;
        } else {
            #pragma unroll
            for (int r = 0; r < 4; r++)
                if (rbase + r < N) dst[r] = f2b(acc[r]);
        }
    } else {
        float bias = (mode == 1) ? bk[colr] : 0.f;
        unsigned short* dst = ((mode == 0) ? qbh : kbh) + (size_t)hh * 2048 * 32 + d;
        #pragma unroll
        for (int r = 0; r < 4; r++) {
            int row = rbase + r;
            if (row < N) {
                float v = acc[r] + bias;
                if (mode == 0) v *= 0.25506362f;
                dst[(size_t)row * 32] = f2b(v);
            }
        }
    }
}

// ---------------------------------------------------------------------------
// MFMA flash attention, one (q0,h) block with fused split-K combine
// (verified rounds 2-4 body).
// ---------------------------------------------------------------------------
__device__ __forceinline__ void attn_one(
    float (*sm_m)[32], float (*sm_l)[32], float (*sm_acc)[32][36],
    int q0, int h,
    const unsigned short* __restrict__ qbh,
    const unsigned short* __restrict__ kbh,
    const unsigned short* __restrict__ vbT,
    unsigned short* __restrict__ obb)
{
    int tid = threadIdx.x;
    int w = tid >> 6;                     // wave = K-chunk
    int lane = tid & 63;
    int l31 = lane & 31, hf = lane >> 5;
    int kstart = w * 512;
    int kend = min(kstart + 512, S_ROWS);

    const unsigned short* qp = qbh + ((size_t)h * 2048 + (q0 + l31)) * 32 + hf * 8;
    bf16x8 qf0 = *(const bf16x8*)(qp);
    bf16x8 qf1 = *(const bf16x8*)(qp + 16);

    const unsigned short* kb_h = kbh + (size_t)h * 2048 * 32;
    const unsigned short* vb_h = vbT + ((size_t)h * 32 + l31) * 2048;

    f32x16 acc = {};
    float m = -1e30f, l = 0.f;

    for (int key0 = kstart; key0 < kend; key0 += 32) {
        const unsigned short* kp = kb_h + (size_t)(key0 + l31) * 32 + hf * 8;
        bf16x8 kf0 = *(const bf16x8*)(kp);
        bf16x8 kf1 = *(const bf16x8*)(kp + 16);
        bf16x8 vf0 = *(const bf16x8*)(vb_h + key0 + hf * 8);
        bf16x8 vf1 = *(const bf16x8*)(vb_h + key0 + 16 + hf * 8);

        f32x16 sc = {};
        sc = __builtin_amdgcn_mfma_f32_32x32x16_bf16(kf0, qf0, sc, 0, 0, 0);
        sc = __builtin_amdgcn_mfma_f32_32x32x16_bf16(kf1, qf1, sc, 0, 0, 0);

        if (key0 + 32 > kend) {
            #pragma unroll
            for (int r = 0; r < 16; r++) {
                int kr = key0 + (r & 3) + 8 * (r >> 2) + 4 * hf;
                if (kr >= kend) sc[r] = -1e30f;
            }
        }
        float tmax = sc[0];
        #pragma unroll
        for (int r = 1; r < 16; r++) tmax = fmaxf(tmax, sc[r]);
        tmax = fmaxf(tmax, __shfl_xor(tmax, 32, 64));
        float mnew = fmaxf(m, tmax);
        float corr = __builtin_amdgcn_exp2f(m - mnew);
        m = mnew;
        float p[16];
        float ls = 0.f;
        #pragma unroll
        for (int r = 0; r < 16; r++) {
            p[r] = __builtin_amdgcn_exp2f(sc[r] - mnew);
            ls += p[r];
        }
        ls += __shfl_xor(ls, 32, 64);
        l = l * corr + ls;
        if (__ballot(corr != 1.0f)) {
            #pragma unroll
            for (int r = 0; r < 16; r++) acc[r] *= corr;
        }
        unsigned int pk[8];
        #pragma unroll
        for (int i = 0; i < 8; i++)
            pk[i] = __builtin_amdgcn_perm(__float_as_uint(p[2*i+1]),
                                          __float_as_uint(p[2*i]), 0x07060302u);
        unsigned int x[8];
        #pragma unroll
        for (int i = 0; i < 8; i++)
            x[i] = (unsigned int)__shfl_xor((int)pk[i], 32, 64);
        union { unsigned int u[4]; bf16x8 v; } B1, B2;
        B1.u[0] = hf ? x[2]  : pk[0];
        B1.u[1] = hf ? x[3]  : pk[1];
        B1.u[2] = hf ? pk[2] : x[0];
        B1.u[3] = hf ? pk[3] : x[1];
        B2.u[0] = hf ? x[6]  : pk[4];
        B2.u[1] = hf ? x[7]  : pk[5];
        B2.u[2] = hf ? pk[6] : x[4];
        B2.u[3] = hf ? pk[7] : x[5];
        acc = __builtin_amdgcn_mfma_f32_32x32x16_bf16(vf0, B1.v, acc, 0, 0, 0);
        acc = __builtin_amdgcn_mfma_f32_32x32x16_bf16(vf1, B2.v, acc, 0, 0, 0);
    }

    // ---- in-block split-K combine through LDS ----
    if (!hf) { sm_m[w][l31] = m; sm_l[w][l31] = l; }
    #pragma unroll
    for (int g = 0; g < 4; g++) {
        float4 o4;
        o4.x = acc[4*g]; o4.y = acc[4*g+1]; o4.z = acc[4*g+2]; o4.w = acc[4*g+3];
        *(float4*)&sm_acc[w][l31][8*g + 4*hf] = o4;
    }
    __syncthreads();

    int q = tid & 31;
    int dg = tid >> 5;
    float mmax = fmaxf(fmaxf(sm_m[0][q], sm_m[1][q]),
                       fmaxf(sm_m[2][q], sm_m[3][q]));
    float lsum = 0.f;
    float num0 = 0.f, num1 = 0.f, num2 = 0.f, num3 = 0.f;
    #pragma unroll
    for (int c = 0; c < 4; c++) {
        float wgt = __builtin_amdgcn_exp2f(sm_m[c][q] - mmax);
        lsum += sm_l[c][q] * wgt;
        float4 o4 = *(const float4*)&sm_acc[c][q][dg * 4];
        num0 = fmaf(o4.x, wgt, num0);
        num1 = fmaf(o4.y, wgt, num1);
        num2 = fmaf(o4.z, wgt, num2);
        num3 = fmaf(o4.w, wgt, num3);
    }
    float inv = 1.f / lsum;
    if (q0 + q < S_ROWS) {
        u16x4 st;
        st[0] = f2b(num0 * inv); st[1] = f2b(num1 * inv);
        st[2] = f2b(num2 * inv); st[3] = f2b(num3 * inv);
        *(u16x4*)(obb + (size_t)(q0 + q) * DIM + h * DH + dg * 4) = st;
    }
    __syncthreads();
}

// ---------------------------------------------------------------------------
// RQS spline for one row (verified rounds 2-3 body).
// ---------------------------------------------------------------------------
__device__ __forceinline__ float spline_row(const float* p, float x, float* yout)
{
    float xc = fminf(fmaxf(x, 0.f), 1.f);
    float mw = -1e30f, mh = -1e30f;
    #pragma unroll
    for (int j = 0; j < NBINS; j++) {
        mw = fmaxf(mw, p[j]);
        mh = fmaxf(mh, p[NBINS + j]);
    }
    float sw = 0.f, shs = 0.f;
    #pragma unroll
    for (int j = 0; j < NBINS; j++) {
        sw += __expf(p[j] - mw);
        shs += __expf(p[NBINS + j] - mh);
    }
    const float span = 1.0f - NBINS * 1e-4f;
    float scw = span / sw, sch = span / shs;
    float cumw = 0.f, cumh = 0.f;
    float xk = 0.f, yk = 0.f, wk = 0.f, hk = 0.f;
    int k = 0;
    #pragma unroll
    for (int j = 0; j < NBINS; j++) {
        float wj = __expf(p[j] - mw) * scw + 1e-4f;
        float hj = __expf(p[NBINS + j] - mh) * sch + 1e-4f;
        if (xc >= cumw) { k = j; xk = cumw; yk = cumh; wk = wj; hk = hj; }
        cumw += wj; cumh += hj;
    }
    float offset = logf(expm1f(0.9999f));
    float t0 = p[2 * NBINS + k] + offset;
    float t1 = ((k == NBINS - 1) ? p[2 * NBINS] : p[2 * NBINS + k + 1]) + offset;
    float dk  = ((t0 > 15.f) ? t0 : log1pf(__expf(t0))) + 1e-4f;
    float dk1 = ((t1 > 15.f) ? t1 : log1pf(__expf(t1))) + 1e-4f;
    float sl = hk / wk;
    float z = (xc - xk) / wk;
    float z1 = 1.f - z;
    float den = sl + (dk1 + dk - 2.f * sl) * z * z1;
    float y = yk + hk * (sl * z * z + dk * z * z1) / den;
    float ldv = 2.f * logf(sl)
              + logf(dk1 * z * z + 2.f * sl * z * z1 + dk * z1 * z1)
              - 2.f * logf(den);
    bool inside = (x >= 0.f) && (x <= 1.f);
    *yout = inside ? y : x;
    return inside ? ldv : 0.f;
}

// ---------------------------------------------------------------------------
// Cooperative mega-kernel: all 32 phases, grid syncs instead of launches.
// 512 blocks x 256 threads (2 blocks/CU co-resident). 19.5 KB LDS arena.
// ---------------------------------------------------------------------------
struct MegaParams {
    const float *pos, *scale, *press, *temp, *e_w0;
    const float *e_b0, *e_b1, *e_b2, *bk, *bo, *mb0, *mb1, *mb2;
    const float *a_b0, *a_b1, *a_b2;
    const float *s0,*s1,*s2,*s3,*s4,*s5,*s6,*s7,*s8,*s9,*s10,*s11;
    unsigned short *wbp, *cond, *t1b, *t2b, *hb, *obb, *qbh, *kbh, *vbT;
    float *hbuf, *pr, *out;
};

#define SMEM_BYTES 19456

__global__ __launch_bounds__(256, 2) void mega_kernel(MegaParams P)
{
    cg::grid_group grid = cg::this_grid();
    __shared__ __align__(16) char smem[SMEM_BYTES];
    unsigned short (*As)[LDK] = (unsigned short(*)[LDK])smem;
    unsigned short (*Bs)[LDK] = (unsigned short(*)[LDK])(smem + 32 * LDK * 2);
    float (*sm_m)[32]     = (float(*)[32])smem;
    float (*sm_l)[32]     = (float(*)[32])(smem + 512);
    float (*sm_acc)[32][36] = (float(*)[32][36])(smem + 1024);

    const int nb = gridDim.x;             // 512
    const int bid = blockIdx.x;

    // ---- phase S: setup ----
    setup_body(bid * 256 + threadIdx.x, nb * 256,
               P.pos, P.scale, P.press, P.temp, P.e_w0,
               P.s0, P.s1, P.s2, P.s3, P.s4, P.s5, P.s6, P.s7, P.s8, P.s9,
               P.s10, P.s11, P.wbp, P.cond, P.out);
    grid.sync();

    auto gphase = [&](const unsigned short* A, const unsigned short* W,
                      const float* bias, const float* resF, float* Cf,
                      unsigned short* Cb, int M, int K, int relu) {
        int nx = (M + 31) >> 5;
        int nt = nx << 6;                 // nx * 64 row tiles
        for (int t = bid; t < nt; t += nb)
            gemm_tile_one(As, Bs, (t / nx) << 5, (t % nx) << 5,
                          A, W, bias, resF, Cf, Cb, M, K, relu);
        grid.sync();
    };

    // ---- embedding MLP ----
    gphase(P.cond, P.wbp + OFF_EW0, P.e_b0, nullptr, nullptr, P.t1b, 512, 64, 1);
    gphase(P.t1b,  P.wbp + OFF_EW1, P.e_b1, nullptr, nullptr, P.t2b, 512, 512, 1);
    gphase(P.t2b,  P.wbp + OFF_EW2, P.e_b2, nullptr, P.hbuf, P.hb, 256, 512, 0);

    for (int l = 0; l < 4; l++) {
        // qkv: 1536 tiles (24 x 64)
        for (int t = bid; t < 1536; t += nb)
            qkv_tile_one(As, Bs, (t / 24) << 5, (t % 24) << 5,
                         P.hb, P.wbp + OFF_WQ + l * 65536, P.wbp + OFF_WK + l * 65536,
                         P.wbp + OFF_WV + l * 65536, P.bk + l * 256,
                         P.qbh, P.kbh, P.vbT);
        grid.sync();
        // attention: 512 tiles (64 q-tiles x 8 heads)
        for (int t = bid; t < 512; t += nb)
            attn_one(sm_m, sm_l, sm_acc, (t >> 3) << 5, t & 7,
                     P.qbh, P.kbh, P.vbT, P.obb);
        grid.sync();
        gphase(P.obb, P.wbp + OFF_WO + l * 65536, P.bo + l * 256, P.hbuf,
               P.hbuf, P.hb, 256, 256, 0);
        gphase(P.hb,  P.wbp + OFF_MW0 + l * 131072, P.mb0 + l * 512, nullptr,
               nullptr, P.t1b, 512, 256, 1);
        gphase(P.t1b, P.wbp + OFF_MW1 + l * 262144, P.mb1 + l * 512, nullptr,
               nullptr, P.t2b, 512, 512, 1);
        gphase(P.t2b, P.wbp + OFF_MW2 + l * 131072, P.mb2 + l * 256, P.hbuf,
               P.hbuf, P.hb, 256, 512, 0);
    }

    // ---- affine-param MLP ----
    gphase(P.hb,  P.wbp + OFF_AW0, P.a_b0, nullptr, nullptr, P.t1b, 512, 256, 1);
    gphase(P.t1b, P.wbp + OFF_AW1, P.a_b1, nullptr, nullptr, P.t2b, 512, 512, 1);
    gphase(P.t2b, P.wbp + OFF_AW2, P.a_b2, nullptr, P.pr, nullptr, AFF_OUT, 512, 0);

    // ---- spline ----
    {
        int r = bid * 256 + threadIdx.x;
        float ld = 0.f;
        if (r < S_ROWS) {
            float x = P.pos[(r + 1) * 3 + 2];
            float y;
            ld = spline_row(P.pr + (size_t)r * AFF_OUT, x, &y);
            P.out[(r + 1) * 3 + 2] = y;
        }
        #pragma unroll
        for (int st = 32; st > 0; st >>= 1) ld += __shfl_xor(ld, st, 64);
        if ((threadIdx.x & 63) == 0 && r < S_ROWS) atomicAdd(&P.out[6144], ld);
    }
}

// ---------------------------------------------------------------------------
// Fallback kernels (bit-identical round-4 behavior) used if cooperative
// launch is unavailable.
// ---------------------------------------------------------------------------
__global__ __launch_bounds__(256) void setup_kernel(
    const float* __restrict__ pos, const float* __restrict__ scale,
    const float* __restrict__ press, const float* __restrict__ temp,
    const float* __restrict__ e_w0, const float* __restrict__ p0,
    const float* __restrict__ p1, const float* __restrict__ p2,
    const float* __restrict__ p3, const float* __restrict__ p4,
    const float* __restrict__ p5, const float* __restrict__ p6,
    const float* __restrict__ p7, const float* __restrict__ p8,
    const float* __restrict__ p9, const float* __restrict__ p10,
    const float* __restrict__ p11, unsigned short* __restrict__ dst,
    unsigned short* __restrict__ cond, float* __restrict__ out)
{
    setup_body(blockIdx.x * blockDim.x + threadIdx.x, gridDim.x * blockDim.x,
               pos, scale, press, temp, e_w0,
               p0,p1,p2,p3,p4,p5,p6,p7,p8,p9,p10,p11, dst, cond, out);
}

__global__ __launch_bounds__(256, 4) void gemm_bf16(
    const unsigned short* __restrict__ Ab, const unsigned short* __restrict__ W,
    const float* __restrict__ bias, const float* resF,
    float* Cf, unsigned short* Cb, int M, int K, int relu)
{
    __shared__ unsigned short As[32][LDK];
    __shared__ unsigned short Bs[32][LDK];
    gemm_tile_one(As, Bs, blockIdx.y << 5, blockIdx.x << 5,
                  Ab, W, bias, resF, Cf, Cb, M, K, relu);
}

__global__ __launch_bounds__(256, 4) void gemm_qkv(
    const unsigned short* __restrict__ Ab, const unsigned short* __restrict__ Wq,
    const unsigned short* __restrict__ Wk, const unsigned short* __restrict__ Wv,
    const float* __restrict__ bk,
    unsigned short* __restrict__ qbh, unsigned short* __restrict__ kbh,
    unsigned short* __restrict__ vbT)
{
    __shared__ unsigned short As[32][LDK];
    __shared__ unsigned short Bs[32][LDK];
    qkv_tile_one(As, Bs, blockIdx.y << 5, blockIdx.x << 5,
                 Ab, Wq, Wk, Wv, bk, qbh, kbh, vbT);
}

__global__ __launch_bounds__(256, 2) void attn_mfma(
    const unsigned short* __restrict__ qbh,
    const unsigned short* __restrict__ kbh,
    const unsigned short* __restrict__ vbT,
    unsigned short* __restrict__ obb)
{
    __shared__ float sm_m[4][32];
    __shared__ float sm_l[4][32];
    __shared__ float sm_acc[4][32][36];
    attn_one(sm_m, sm_l, sm_acc, blockIdx.x << 5, blockIdx.y,
             qbh, kbh, vbT, obb);
}

__global__ __launch_bounds__(64) void spline_kernel(const float* __restrict__ pos,
    const float* __restrict__ params, float* __restrict__ out)
{
    int r = blockIdx.x * 64 + threadIdx.x;
    float ld = 0.f;
    if (r < S_ROWS) {
        float x = pos[(r + 1) * 3 + 2];
        float y;
        ld = spline_row(params + (size_t)r * AFF_OUT, x, &y);
        out[(r + 1) * 3 + 2] = y;
    }
    #pragma unroll
    for (int st = 32; st > 0; st >>= 1) ld += __shfl_xor(ld, st, 64);
    if (threadIdx.x == 0) atomicAdd(&out[6144], ld);
}

// ---------------------------------------------------------------------------
extern "C" void kernel_launch(void* const* d_in, const int* in_sizes, int n_in,
                              void* d_out, int out_size, void* d_ws, size_t ws_size,
                              hipStream_t stream)
{
    const float* pos   = (const float*)d_in[0];
    const float* scale = (const float*)d_in[1];
    const float* press = (const float*)d_in[2];
    const float* temp  = (const float*)d_in[3];
    const float* e_w0  = (const float*)d_in[4];
    const float* e_b0  = (const float*)d_in[5];
    const float* e_w1  = (const float*)d_in[6];
    const float* e_b1  = (const float*)d_in[7];
    const float* e_w2  = (const float*)d_in[8];
    const float* e_b2  = (const float*)d_in[9];
    const float* Wq    = (const float*)d_in[10];
    const float* Wk    = (const float*)d_in[11];
    const float* bk    = (const float*)d_in[12];
    const float* Wv    = (const float*)d_in[13];
    const float* Wo    = (const float*)d_in[14];
    const float* bo    = (const float*)d_in[15];
    const float* mw0   = (const float*)d_in[16];
    const float* mb0   = (const float*)d_in[17];
    const float* mw1   = (const float*)d_in[18];
    const float* mb1   = (const float*)d_in[19];
    const float* mw2   = (const float*)d_in[20];
    const float* mb2   = (const float*)d_in[21];
    const float* a_w0  = (const float*)d_in[22];
    const float* a_b0  = (const float*)d_in[23];
    const float* a_w1  = (const float*)d_in[24];
    const float* a_b1  = (const float*)d_in[25];
    const float* a_w2  = (const float*)d_in[26];
    const float* a_b2  = (const float*)d_in[27];
    float* out = (float*)d_out;

    const size_t WB_U16 = (size_t)EW0P_N + W_MAIN;   // 3990016

    float* ws = (float*)d_ws;
    size_t off = 0;
    float* hbuf = ws + off; off += 2048 * 256;             // f32 residual stream
    float* pr   = ws + off; off += 2048 * 64;              // spline params f32
    unsigned short* wbp   = (unsigned short*)(ws + off); off += WB_U16 / 2;
    unsigned short* cond  = (unsigned short*)(ws + off); off += 2048 * 64 / 2;
    unsigned short* t1b   = (unsigned short*)(ws + off); off += 2048 * 512 / 2;
    unsigned short* t2b   = (unsigned short*)(ws + off); off += 2048 * 512 / 2;
    unsigned short* hb    = (unsigned short*)(ws + off); off += 2048 * 256 / 2;
    unsigned short* obb   = (unsigned short*)(ws + off); off += 2048 * 256 / 2;
    unsigned short* qbh   = (unsigned short*)(ws + off); off += NHEADS * 2048 * 32 / 2;
    unsigned short* kbh   = (unsigned short*)(ws + off); off += NHEADS * 2048 * 32 / 2;
    unsigned short* vbT   = (unsigned short*)(ws + off); off += NHEADS * 2048 * 32 / 2;
    (void)ws_size;

    // ---- cooperative mega-kernel path ----
    MegaParams P;
    P.pos = pos; P.scale = scale; P.press = press; P.temp = temp; P.e_w0 = e_w0;
    P.e_b0 = e_b0; P.e_b1 = e_b1; P.e_b2 = e_b2; P.bk = bk; P.bo = bo;
    P.mb0 = mb0; P.mb1 = mb1; P.mb2 = mb2;
    P.a_b0 = a_b0; P.a_b1 = a_b1; P.a_b2 = a_b2;
    P.s0 = e_w1; P.s1 = e_w2; P.s2 = Wq; P.s3 = Wk; P.s4 = Wv; P.s5 = Wo;
    P.s6 = mw0; P.s7 = mw1; P.s8 = mw2; P.s9 = a_w0; P.s10 = a_w1; P.s11 = a_w2;
    P.wbp = wbp; P.cond = cond; P.t1b = t1b; P.t2b = t2b; P.hb = hb;
    P.obb = obb; P.qbh = qbh; P.kbh = kbh; P.vbT = vbT;
    P.hbuf = hbuf; P.pr = pr; P.out = out;

    void* kargs[] = { (void*)&P };
    hipError_t rc = hipLaunchCooperativeKernel((const void*)mega_kernel,
                                               dim3(512), dim3(256), kargs, 0, stream);
    if (rc == hipSuccess) return;
    (void)hipGetLastError();              // clear error, fall back

    // ---- fallback: round-4 multi-launch path (verified 343 us) ----
    enum { F_EW0 = OFF_EW0, F_EW1 = OFF_EW1, F_EW2 = OFF_EW2,
           F_WQ = OFF_WQ, F_WK = OFF_WK, F_WV = OFF_WV, F_WO = OFF_WO,
           F_MW0 = OFF_MW0, F_MW1 = OFF_MW1, F_MW2 = OFF_MW2,
           F_AW0 = OFF_AW0, F_AW1 = OFF_AW1, F_AW2 = OFF_AW2 };

    hipLaunchKernelGGL(setup_kernel, dim3(1024), dim3(256), 0, stream,
                       pos, scale, press, temp, e_w0,
                       e_w1, e_w2, Wq, Wk, Wv, Wo, mw0, mw1, mw2,
                       a_w0, a_w1, a_w2, wbp, cond, out);

    auto gemm = [&](const unsigned short* A, const unsigned short* W,
                    const float* bias, const float* resF, float* Cf,
                    unsigned short* Cb, int M, int K, int relu) {
        dim3 grid((M + 31) / 32, 64);
        hipLaunchKernelGGL(gemm_bf16, grid, dim3(256), 0, stream,
                           A, W, bias, resF, Cf, Cb, M, K, relu);
    };

    gemm(cond, wbp + F_EW0, e_b0, nullptr, nullptr, t1b, 512, 64, 1);
    gemm(t1b,  wbp + F_EW1, e_b1, nullptr, nullptr, t2b, 512, 512, 1);
    gemm(t2b,  wbp + F_EW2, e_b2, nullptr, hbuf, hb, 256, 512, 0);

    for (int l = 0; l < 4; l++) {
        hipLaunchKernelGGL(gemm_qkv, dim3(24, 64), dim3(256), 0, stream,
                           hb, wbp + F_WQ + l * 65536, wbp + F_WK + l * 65536,
                           wbp + F_WV + l * 65536, bk + l * 256, qbh, kbh, vbT);
        hipLaunchKernelGGL(attn_mfma, dim3(64, NHEADS), dim3(256), 0, stream,
                           qbh, kbh, vbT, obb);
        gemm(obb, wbp + F_WO + l * 65536, bo + l * 256, hbuf, hbuf, hb, 256, 256, 0);
        gemm(hb,  wbp + F_MW0 + l * 131072, mb0 + l * 512, nullptr, nullptr, t1b, 512, 256, 1);
        gemm(t1b, wbp + F_MW1 + l * 262144, mb1 + l * 512, nullptr, nullptr, t2b, 512, 512, 1);
        gemm(t2b, wbp + F_MW2 + l * 131072, mb2 + l * 256, hbuf, hbuf, hb, 256, 512, 0);
    }

    gemm(hb,  wbp + F_AW0, a_b0, nullptr, nullptr, t1b, 512, 256, 1);
    gemm(t1b, wbp + F_AW1, a_b1, nullptr, nullptr, t2b, 512, 512, 1);
    gemm(t2b, wbp + F_AW2, a_b2, nullptr, pr, nullptr, AFF_OUT, 512, 0);

    hipLaunchKernelGGL(spline_kernel, dim3(32), dim3(64), 0, stream, pos, pr, out);
}

// Round 6
// 409.789 us; speedup vs baseline: 5.1609x; 5.1609x over previous
//
#include <hip/hip_runtime.h>
#include <math.h>

#define S_ROWS 2047
#define DIM 256
#define HID 512
#define NHEADS 8
#define DH 32
#define NBINS 16
#define AFF_OUT 49

typedef short bf16x8 __attribute__((ext_vector_type(8)));
typedef float f32x4 __attribute__((ext_vector_type(4)));
typedef float f32x16 __attribute__((ext_vector_type(16)));
typedef unsigned short u16x8 __attribute__((ext_vector_type(8)));
typedef unsigned short u16x4 __attribute__((ext_vector_type(4)));

__device__ inline unsigned short f2b(float f) {
    unsigned int u = __float_as_uint(f);
    u += 0x7FFFu + ((u >> 16) & 1u);      // round-to-nearest-even
    return (unsigned short)(u >> 16);
}

// bf16 weight region offsets (u16 elements): [ew0p | main segments]
#define OFF_EW0 0
#define OFF_EW1 (32768 + 0)
#define OFF_EW2 (32768 + 262144)
#define OFF_WQ  (32768 + 393216)
#define OFF_WK  (32768 + 655360)
#define OFF_WV  (32768 + 917504)
#define OFF_WO  (32768 + 1179648)
#define OFF_MW0 (32768 + 1441792)
#define OFF_MW1 (32768 + 1966080)
#define OFF_MW2 (32768 + 3014656)
#define OFF_AW0 (32768 + 3538944)
#define OFF_AW1 (32768 + 3670016)
#define OFF_AW2 (32768 + 3932160)

// ---------------------------------------------------------------------------
// Fused setup (verified): weight f32->bf16 (+ew0 zero-pad to K=64),
// circular features, pos copy + out[6144]=0.
// ---------------------------------------------------------------------------
#define W_MAIN 3957248
#define EW0P_N 32768
#define P0 (W_MAIN / 4)
#define P1 (P0 + EW0P_N / 4)
#define P2 (P1 + 2048 * 64 / 4)
#define P3 (P2 + 1537)
__global__ __launch_bounds__(256) void setup_kernel(
    const float* __restrict__ pos, const float* __restrict__ scale,
    const float* __restrict__ press, const float* __restrict__ temp,
    const float* __restrict__ e_w0, const float* __restrict__ p0,
    const float* __restrict__ p1, const float* __restrict__ p2,
    const float* __restrict__ p3, const float* __restrict__ p4,
    const float* __restrict__ p5, const float* __restrict__ p6,
    const float* __restrict__ p7, const float* __restrict__ p8,
    const float* __restrict__ p9, const float* __restrict__ p10,
    const float* __restrict__ p11, unsigned short* __restrict__ dst,
    unsigned short* __restrict__ cond, float* __restrict__ out)
{
    const int offs[13] = {0, 262144, 393216, 655360, 917504, 1179648, 1441792,
                          1966080, 3014656, 3538944, 3670016, 3932160, 3957248};
    const float* srcs[12] = {p0,p1,p2,p3,p4,p5,p6,p7,p8,p9,p10,p11};
    for (int i4 = blockIdx.x * blockDim.x + threadIdx.x; i4 < P3;
         i4 += gridDim.x * blockDim.x) {
        if (i4 < P0) {
            int e = i4 * 4;
            int s = 0;
            #pragma unroll
            for (int j = 1; j < 12; j++) s += (e >= offs[j]);
            const float4 v = *(const float4*)(srcs[s] + (e - offs[s]));
            u16x4 o;
            o[0] = f2b(v.x); o[1] = f2b(v.y); o[2] = f2b(v.z); o[3] = f2b(v.w);
            *(u16x4*)(dst + EW0P_N + e) = o;
        } else if (i4 < P1) {
            int e = (i4 - P0) * 4;
            u16x4 o;
            #pragma unroll
            for (int r = 0; r < 4; r++) {
                int ee = e + r;
                int row = ee >> 6, col = ee & 63;
                o[r] = (col < 35) ? f2b(e_w0[row * 35 + col]) : (unsigned short)0;
            }
            *(u16x4*)(dst + e) = o;
        } else if (i4 < P2) {
            int e = (i4 - P1) * 4;
            int row = e >> 6;
            u16x4 o;
            #pragma unroll
            for (int r = 0; r < 4; r++) {
                int c = (e + r) & 63;
                float v = 0.f;
                if (row < S_ROWS) {
                    if (c < 32) {
                        int coord = c >> 4;
                        int w = c & 15;
                        float x = pos[(row + 1) * 3 + coord];
                        float f = 6.283185307179586f * (float)((w & 7) + 1);
                        float ang = x * f;
                        v = (w < 8) ? cosf(ang) : sinf(ang);
                    } else if (c == 32) v = scale[0];
                    else if (c == 33) v = temp[0];
                    else if (c == 34) v = press[0];
                }
                o[r] = f2b(v);
            }
            *(u16x4*)(cond + e) = o;
        } else {
            int e = (i4 - P2) * 4;
            #pragma unroll
            for (int r = 0; r < 4; r++) {
                int ee = e + r;
                if (ee < 6144) out[ee] = pos[ee];
                else if (ee == 6144) out[ee] = 0.f;
            }
        }
    }
}

// ---------------------------------------------------------------------------
// Row-local chain v3. Block = 8 rows x 512 threads (8 waves), grid 256
// (1 block/CU). Unlike round-3 (per-wave direct W loads, latency-bound),
// W streams through LDS: 512 threads cooperatively stage 128-col x 128-k
// W chunks with the VERIFIED store -> barrier -> reg-prefetch -> MFMA ->
// barrier pipeline. Activations in LDS; MFMA C-rows 8..15 computed from
// dead LDS rows, discarded (row-independent dot products).
// ---------------------------------------------------------------------------
#define LDA 520        // act row stride (u16): 1040B -> 4-bank row shift
#define LDW 136        // W-stage row stride (u16): 272B -> 4-bank row shift
#define LDR 260        // res row stride (f32)

template<int K, int M, bool RELU, int RESMODE>   // RESMODE: 0 none 1 add+upd 2 set
__device__ __forceinline__ void stage_w(
    const unsigned short (*IN)[LDA], unsigned short (*OUT)[LDA],
    float (*res)[LDR], unsigned short (*Wbuf)[LDW],
    const unsigned short* __restrict__ W, const float* __restrict__ bias,
    int tid)
{
    int wv = tid >> 6;
    int lane = tid & 63, quad = lane >> 4, l16 = lane & 15;
    constexpr int NI  = K / 32;                  // A fragments
    constexpr int KS  = (K >= 128) ? 128 : K;    // K-chunk
    constexpr int LPT = KS / 32;                 // u16x8 loads / thread / chunk
    constexpr int NK  = K / KS;
    constexpr int NCT = M / 128;                 // 128-col tiles
    constexpr int NC  = NCT * NK;

    bf16x8 af[NI];
    #pragma unroll
    for (int i = 0; i < NI; i++)
        af[i] = *(const bf16x8*)&IN[l16][(i << 5) + (quad << 3)];

    int wrow = tid >> 2;                         // 0..127 (staged W row)
    int kb = (tid & 3) * (KS / 4);

    f32x4 acc[NCT];
    #pragma unroll
    for (int i = 0; i < NCT; i++) { f32x4 z = {0.f,0.f,0.f,0.f}; acc[i] = z; }

    u16x8 w[LPT];
    {
        const u16x8* wp = (const u16x8*)(W + (size_t)wrow * K + kb);
        #pragma unroll
        for (int j = 0; j < LPT; j++) w[j] = wp[j];
    }
    #pragma unroll
    for (int c = 0; c < NC; c++) {
        int ct = c / NK, kc = c % NK;            // compile-time after unroll
        #pragma unroll
        for (int j = 0; j < LPT; j++)
            *(u16x8*)&Wbuf[wrow][kb + (j << 3)] = w[j];
        __syncthreads();
        if (c + 1 < NC) {                        // prefetch next chunk (in flight)
            int ct2 = (c + 1) / NK, kc2 = (c + 1) % NK;
            const u16x8* np = (const u16x8*)(W + (size_t)(ct2 * 128 + wrow) * K
                                             + kc2 * KS + kb);
            #pragma unroll
            for (int j = 0; j < LPT; j++) w[j] = np[j];
        }
        #pragma unroll
        for (int kt = 0; kt < KS; kt += 32) {
            bf16x8 bf = *(bf16x8*)&Wbuf[(wv << 4) + l16][kt + (quad << 3)];
            acc[ct] = __builtin_amdgcn_mfma_f32_16x16x32_bf16(
                          af[(kc * KS + kt) >> 5], bf, acc[ct], 0, 0, 0);
        }
        __syncthreads();
    }
    #pragma unroll
    for (int ct = 0; ct < NCT; ct++) {
        int col = (ct << 7) + (wv << 4) + l16;
        float bv = bias[col];
        if (quad < 2) {                          // rows 0..7 only
            #pragma unroll
            for (int r = 0; r < 4; r++) {
                int row = (quad << 2) + r;
                float v = acc[ct][r] + bv;
                if (RESMODE == 1) { v += res[row][col]; res[row][col] = v; }
                if (RESMODE == 2) { res[row][col] = v; }
                if (RELU) v = fmaxf(v, 0.f);
                OUT[row][col] = f2b(v);
            }
        }
    }
}

// qkv stage: K=256, M=768 (q|k|v), LDS-staged W, verified epilogue layouts.
__device__ __forceinline__ void stage_qkv_w(
    const unsigned short (*IN)[LDA], unsigned short (*Wbuf)[LDW],
    const unsigned short* __restrict__ Wq, const unsigned short* __restrict__ Wk,
    const unsigned short* __restrict__ Wv, const float* __restrict__ bk,
    unsigned short* __restrict__ qbh, unsigned short* __restrict__ kbh,
    unsigned short* __restrict__ vbT,
    int row0, int tid)
{
    const int K = 256;
    int wv = tid >> 6;
    int lane = tid & 63, quad = lane >> 4, l16 = lane & 15;

    bf16x8 af[8];
    #pragma unroll
    for (int i = 0; i < 8; i++)
        af[i] = *(const bf16x8*)&IN[l16][(i << 5) + (quad << 3)];

    int wrow = tid >> 2;
    int kb = (tid & 3) << 5;                     // KS=128

    f32x4 acc[6];
    #pragma unroll
    for (int i = 0; i < 6; i++) { f32x4 z = {0.f,0.f,0.f,0.f}; acc[i] = z; }

    u16x8 w[4];
    {
        const u16x8* wp = (const u16x8*)(Wq + (size_t)wrow * K + kb);
        #pragma unroll
        for (int j = 0; j < 4; j++) w[j] = wp[j];
    }
    #pragma unroll
    for (int c = 0; c < 12; c++) {               // 6 col-tiles x 2 k-chunks
        int ct = c >> 1, kc = c & 1;
        #pragma unroll
        for (int j = 0; j < 4; j++)
            *(u16x8*)&Wbuf[wrow][kb + (j << 3)] = w[j];
        __syncthreads();
        if (c + 1 < 12) {
            int ct2 = (c + 1) >> 1, kc2 = (c + 1) & 1;
            const unsigned short* base = (ct2 < 2) ? Wq : (ct2 < 4) ? Wk : Wv;
            const u16x8* np = (const u16x8*)(base
                + (size_t)(((ct2 & 1) << 7) + wrow) * K + kc2 * 128 + kb);
            #pragma unroll
            for (int j = 0; j < 4; j++) w[j] = np[j];
        }
        #pragma unroll
        for (int kt = 0; kt < 128; kt += 32) {
            bf16x8 bf = *(bf16x8*)&Wbuf[(wv << 4) + l16][kt + (quad << 3)];
            acc[ct] = __builtin_amdgcn_mfma_f32_16x16x32_bf16(
                          af[(kc * 128 + kt) >> 5], bf, acc[ct], 0, 0, 0);
        }
        __syncthreads();
    }
    #pragma unroll
    for (int ct = 0; ct < 6; ct++) {
        if (quad >= 2) continue;                 // rows 0..7 only
        int col = (ct << 7) + (wv << 4) + l16;   // 0..767
        int mode = col >> 8;
        int colr = col & 255;
        int hh = colr >> 5, d = colr & 31;
        int rbase = row0 + (quad << 2);
        if (mode == 2) {
            unsigned short* dst = vbT + ((size_t)hh * 32 + d) * 2048 + rbase;
            if (rbase + 3 < S_ROWS) {
                u16x4 o;
                #pragma unroll
                for (int r = 0; r < 4; r++) o[r] = f2b(acc[ct][r]);
                *(u16x4*)dst = o;
            } else {
                #pragma unroll
                for (int r = 0; r < 4; r++)
                    if (rbase + r < S_ROWS) dst[r] = f2b(acc[ct][r]);
            }
        } else {
            float bias = (mode == 1) ? bk[colr] : 0.f;
            unsigned short* dst = ((mode == 0) ? qbh : kbh) + (size_t)hh * 2048 * 32 + d;
            #pragma unroll
            for (int r = 0; r < 4; r++) {
                int row = rbase + r;
                if (row < S_ROWS) {
                    float v = acc[ct][r] + bias;
                    if (mode == 0) v *= 0.25506362f;
                    dst[(size_t)row * 32] = f2b(v);
                }
            }
        }
    }
}

// RQS spline for one row (verified).
__device__ __forceinline__ float spline_row(const float* p, float x, float* yout)
{
    float xc = fminf(fmaxf(x, 0.f), 1.f);
    float mw = -1e30f, mh = -1e30f;
    #pragma unroll
    for (int j = 0; j < NBINS; j++) {
        mw = fmaxf(mw, p[j]);
        mh = fmaxf(mh, p[NBINS + j]);
    }
    float sw = 0.f, shs = 0.f;
    #pragma unroll
    for (int j = 0; j < NBINS; j++) {
        sw += __expf(p[j] - mw);
        shs += __expf(p[NBINS + j] - mh);
    }
    const float span = 1.0f - NBINS * 1e-4f;
    float scw = span / sw, sch = span / shs;
    float cumw = 0.f, cumh = 0.f;
    float xk = 0.f, yk = 0.f, wk = 0.f, hk = 0.f;
    int k = 0;
    #pragma unroll
    for (int j = 0; j < NBINS; j++) {
        float wj = __expf(p[j] - mw) * scw + 1e-4f;
        float hj = __expf(p[NBINS + j] - mh) * sch + 1e-4f;
        if (xc >= cumw) { k = j; xk = cumw; yk = cumh; wk = wj; hk = hj; }
        cumw += wj; cumh += hj;
    }
    float offset = logf(expm1f(0.9999f));
    float t0 = p[2 * NBINS + k] + offset;
    float t1 = ((k == NBINS - 1) ? p[2 * NBINS] : p[2 * NBINS + k + 1]) + offset;
    float dk  = ((t0 > 15.f) ? t0 : log1pf(__expf(t0))) + 1e-4f;
    float dk1 = ((t1 > 15.f) ? t1 : log1pf(__expf(t1))) + 1e-4f;
    float sl = hk / wk;
    float z = (xc - xk) / wk;
    float z1 = 1.f - z;
    float den = sl + (dk1 + dk - 2.f * sl) * z * z1;
    float y = yk + hk * (sl * z * z + dk * z * z1) / den;
    float ldv = 2.f * logf(sl)
              + logf(dk1 * z * z + 2.f * sl * z * z1 + dk * z1 * z1)
              - 2.f * logf(den);
    bool inside = (x >= 0.f) && (x <= 1.f);
    *yout = inside ? y : x;
    return inside ? ldv : 0.f;
}

__global__ __launch_bounds__(512, 2) void chain_kernel(
    int mode,
    const unsigned short* __restrict__ wbp,
    const unsigned short* __restrict__ cond,
    const unsigned short* __restrict__ obb,
    float* __restrict__ hbuf,
    unsigned short* __restrict__ qbh, unsigned short* __restrict__ kbh,
    unsigned short* __restrict__ vbT,
    const float* __restrict__ e_b0, const float* __restrict__ e_b1,
    const float* __restrict__ e_b2,
    const float* __restrict__ bo, const float* __restrict__ mb0,
    const float* __restrict__ mb1, const float* __restrict__ mb2,
    const float* __restrict__ bk,
    const float* __restrict__ a_b0, const float* __restrict__ a_b1,
    const float* __restrict__ a_b2,
    const float* __restrict__ pos, float* __restrict__ out)
{
    __shared__ unsigned short actA[16][LDA];   // rows 8..15 dead (MFMA garbage)
    __shared__ unsigned short actB[16][LDA];
    __shared__ unsigned short Wbuf[128][LDW];
    __shared__ float res[8][LDR];
    __shared__ float pl[8][52];

    int tid = threadIdx.x;
    int wv = tid >> 6, lane = tid & 63;
    int quad = lane >> 4, l16 = lane & 15;
    int row0 = blockIdx.x << 3;                // 8 rows per block, 256 blocks

    if (mode < 0) {
        // ---- embedding chain + qkv layer 0 ----
        if (tid < 64) {
            int r = tid >> 3, c = (tid & 7) << 3;
            *(u16x8*)&actA[r][c] = *(const u16x8*)(cond + (size_t)(row0 + r) * 64 + c);
        }
        __syncthreads();
        stage_w<64, 512, true, 0>(actA, actB, res, Wbuf, wbp + OFF_EW0, e_b0, tid);
        __syncthreads();
        stage_w<512, 512, true, 0>(actB, actA, res, Wbuf, wbp + OFF_EW1, e_b1, tid);
        __syncthreads();
        stage_w<512, 256, false, 2>(actA, actB, res, Wbuf, wbp + OFF_EW2, e_b2, tid);
        __syncthreads();
        if (tid < 256) {   // residual -> hbuf (8 rows x 256 cols)
            int r = tid >> 5, c = (tid & 31) << 3;
            *(float4*)(hbuf + (size_t)(row0 + r) * 256 + c)     = *(float4*)&res[r][c];
            *(float4*)(hbuf + (size_t)(row0 + r) * 256 + c + 4) = *(float4*)&res[r][c + 4];
        }
        stage_qkv_w(actB, Wbuf, wbp + OFF_WQ, wbp + OFF_WK, wbp + OFF_WV, bk,
                    qbh, kbh, vbT, row0, tid);
    } else {
        int l = mode;
        if (tid < 256) {   // load attn output + residual (8 rows)
            int r = tid >> 5, c = (tid & 31) << 3;
            *(u16x8*)&actA[r][c] = *(const u16x8*)(obb + (size_t)(row0 + r) * 256 + c);
            *(float4*)&res[r][c]     = *(const float4*)(hbuf + (size_t)(row0 + r) * 256 + c);
            *(float4*)&res[r][c + 4] = *(const float4*)(hbuf + (size_t)(row0 + r) * 256 + c + 4);
        }
        __syncthreads();
        stage_w<256, 256, false, 1>(actA, actB, res, Wbuf, wbp + OFF_WO + l * 65536,
                                    bo + l * 256, tid);
        __syncthreads();
        stage_w<256, 512, true, 0>(actB, actA, res, Wbuf, wbp + OFF_MW0 + l * 131072,
                                   mb0 + l * 512, tid);
        __syncthreads();
        stage_w<512, 512, true, 0>(actA, actB, res, Wbuf, wbp + OFF_MW1 + l * 262144,
                                   mb1 + l * 512, tid);
        __syncthreads();
        stage_w<512, 256, false, 1>(actB, actA, res, Wbuf, wbp + OFF_MW2 + l * 131072,
                                    mb2 + l * 256, tid);
        __syncthreads();
        if (l < 3) {
            if (tid < 256) {   // residual -> hbuf for next layer
                int r = tid >> 5, c = (tid & 31) << 3;
                *(float4*)(hbuf + (size_t)(row0 + r) * 256 + c)     = *(float4*)&res[r][c];
                *(float4*)(hbuf + (size_t)(row0 + r) * 256 + c + 4) = *(float4*)&res[r][c + 4];
            }
            stage_qkv_w(actA, Wbuf, wbp + OFF_WQ + (l + 1) * 65536,
                        wbp + OFF_WK + (l + 1) * 65536, wbp + OFF_WV + (l + 1) * 65536,
                        bk + (l + 1) * 256, qbh, kbh, vbT, row0, tid);
        } else {
            // ---- affine-param chain + spline ----
            stage_w<256, 512, true, 0>(actA, actB, res, Wbuf, wbp + OFF_AW0, a_b0, tid);
            __syncthreads();
            stage_w<512, 512, true, 0>(actB, actA, res, Wbuf, wbp + OFF_AW1, a_b1, tid);
            __syncthreads();
            {   // aff2: K=512, M=49 (64-col tile; W rows clamped to 48)
                bf16x8 af[16];
                #pragma unroll
                for (int i = 0; i < 16; i++)
                    af[i] = *(const bf16x8*)&actA[l16][(i << 5) + (quad << 3)];
                int wrow = tid >> 3;             // 0..63
                int kb = (tid & 7) << 4;         // 0..112
                int wr = (wrow < 49) ? wrow : 48;
                const unsigned short* W2 = wbp + OFF_AW2;
                f32x4 acc = {0.f, 0.f, 0.f, 0.f};
                u16x8 w0, w1;
                {
                    const u16x8* wp = (const u16x8*)(W2 + (size_t)wr * 512 + kb);
                    w0 = wp[0]; w1 = wp[1];
                }
                #pragma unroll
                for (int c = 0; c < 4; c++) {
                    *(u16x8*)&Wbuf[wrow][kb]     = w0;
                    *(u16x8*)&Wbuf[wrow][kb + 8] = w1;
                    __syncthreads();
                    if (c < 3) {
                        const u16x8* np = (const u16x8*)(W2 + (size_t)wr * 512
                                                         + (c + 1) * 128 + kb);
                        w0 = np[0]; w1 = np[1];
                    }
                    if (wv < 4) {
                        #pragma unroll
                        for (int kt = 0; kt < 128; kt += 32) {
                            bf16x8 bf = *(bf16x8*)&Wbuf[(wv << 4) + l16][kt + (quad << 3)];
                            acc = __builtin_amdgcn_mfma_f32_16x16x32_bf16(
                                      af[(c * 128 + kt) >> 5], bf, acc, 0, 0, 0);
                        }
                    }
                    __syncthreads();
                }
                if (wv < 4 && quad < 2) {
                    int col = (wv << 4) + l16;
                    if (col < AFF_OUT) {
                        float bv = a_b2[col];
                        #pragma unroll
                        for (int r = 0; r < 4; r++)
                            pl[(quad << 2) + r][col] = acc[r] + bv;
                    }
                }
            }
            __syncthreads();
            if (tid < 8) {
                float ld = 0.f;
                int grow = row0 + tid;
                if (grow < S_ROWS) {
                    float x = pos[(grow + 1) * 3 + 2];
                    float y;
                    ld = spline_row(&pl[tid][0], x, &y);
                    out[(grow + 1) * 3 + 2] = y;
                }
                #pragma unroll
                for (int st = 4; st > 0; st >>= 1) ld += __shfl_xor(ld, st, 64);
                if (tid == 0) atomicAdd(&out[6144], ld);
            }
        }
    }
}

// ---------------------------------------------------------------------------
// MFMA flash attention with fused split-K combine (verified rounds 2-4).
// Block = 4 waves; wave w owns K-chunk w. Grid (64, 8) = 512 blocks.
// ---------------------------------------------------------------------------
__global__ __launch_bounds__(256, 2) void attn_mfma(
    const unsigned short* __restrict__ qbh,
    const unsigned short* __restrict__ kbh,
    const unsigned short* __restrict__ vbT,
    unsigned short* __restrict__ obb)
{
    int tid = threadIdx.x;
    int w = tid >> 6;                     // wave = K-chunk
    int lane = tid & 63;
    int l31 = lane & 31, hf = lane >> 5;
    int q0 = blockIdx.x << 5;
    int h = blockIdx.y;
    int kstart = w * 512;
    int kend = min(kstart + 512, S_ROWS);

    const unsigned short* qp = qbh + ((size_t)h * 2048 + (q0 + l31)) * 32 + hf * 8;
    bf16x8 qf0 = *(const bf16x8*)(qp);
    bf16x8 qf1 = *(const bf16x8*)(qp + 16);

    const unsigned short* kb_h = kbh + (size_t)h * 2048 * 32;
    const unsigned short* vb_h = vbT + ((size_t)h * 32 + l31) * 2048;

    f32x16 acc = {};
    float m = -1e30f, l = 0.f;

    for (int key0 = kstart; key0 < kend; key0 += 32) {
        const unsigned short* kp = kb_h + (size_t)(key0 + l31) * 32 + hf * 8;
        bf16x8 kf0 = *(const bf16x8*)(kp);
        bf16x8 kf1 = *(const bf16x8*)(kp + 16);
        bf16x8 vf0 = *(const bf16x8*)(vb_h + key0 + hf * 8);
        bf16x8 vf1 = *(const bf16x8*)(vb_h + key0 + 16 + hf * 8);

        f32x16 sc = {};
        sc = __builtin_amdgcn_mfma_f32_32x32x16_bf16(kf0, qf0, sc, 0, 0, 0);
        sc = __builtin_amdgcn_mfma_f32_32x32x16_bf16(kf1, qf1, sc, 0, 0, 0);

        if (key0 + 32 > kend) {
            #pragma unroll
            for (int r = 0; r < 16; r++) {
                int kr = key0 + (r & 3) + 8 * (r >> 2) + 4 * hf;
                if (kr >= kend) sc[r] = -1e30f;
            }
        }
        float tmax = sc[0];
        #pragma unroll
        for (int r = 1; r < 16; r++) tmax = fmaxf(tmax, sc[r]);
        tmax = fmaxf(tmax, __shfl_xor(tmax, 32, 64));
        float mnew = fmaxf(m, tmax);
        float corr = __builtin_amdgcn_exp2f(m - mnew);
        m = mnew;
        float p[16];
        float ls = 0.f;
        #pragma unroll
        for (int r = 0; r < 16; r++) {
            p[r] = __builtin_amdgcn_exp2f(sc[r] - mnew);
            ls += p[r];
        }
        ls += __shfl_xor(ls, 32, 64);
        l = l * corr + ls;
        if (__ballot(corr != 1.0f)) {
            #pragma unroll
            for (int r = 0; r < 16; r++) acc[r] *= corr;
        }
        unsigned int pk[8];
        #pragma unroll
        for (int i = 0; i < 8; i++)
            pk[i] = __builtin_amdgcn_perm(__float_as_uint(p[2*i+1]),
                                          __float_as_uint(p[2*i]), 0x07060302u);
        unsigned int x[8];
        #pragma unroll
        for (int i = 0; i < 8; i++)
            x[i] = (unsigned int)__shfl_xor((int)pk[i], 32, 64);
        union { unsigned int u[4]; bf16x8 v; } B1, B2;
        B1.u[0] = hf ? x[2]  : pk[0];
        B1.u[1] = hf ? x[3]  : pk[1];
        B1.u[2] = hf ? pk[2] : x[0];
        B1.u[3] = hf ? pk[3] : x[1];
        B2.u[0] = hf ? x[6]  : pk[4];
        B2.u[1] = hf ? x[7]  : pk[5];
        B2.u[2] = hf ? pk[6] : x[4];
        B2.u[3] = hf ? pk[7] : x[5];
        acc = __builtin_amdgcn_mfma_f32_32x32x16_bf16(vf0, B1.v, acc, 0, 0, 0);
        acc = __builtin_amdgcn_mfma_f32_32x32x16_bf16(vf1, B2.v, acc, 0, 0, 0);
    }

    // ---- in-block split-K combine through LDS ----
    __shared__ float sm_m[4][32];
    __shared__ float sm_l[4][32];
    __shared__ float sm_acc[4][32][36];
    if (!hf) { sm_m[w][l31] = m; sm_l[w][l31] = l; }
    #pragma unroll
    for (int g = 0; g < 4; g++) {
        float4 o4;
        o4.x = acc[4*g]; o4.y = acc[4*g+1]; o4.z = acc[4*g+2]; o4.w = acc[4*g+3];
        *(float4*)&sm_acc[w][l31][8*g + 4*hf] = o4;
    }
    __syncthreads();

    int q = tid & 31;
    int dg = tid >> 5;
    float mmax = fmaxf(fmaxf(sm_m[0][q], sm_m[1][q]),
                       fmaxf(sm_m[2][q], sm_m[3][q]));
    float lsum = 0.f;
    float num0 = 0.f, num1 = 0.f, num2 = 0.f, num3 = 0.f;
    #pragma unroll
    for (int c = 0; c < 4; c++) {
        float wgt = __builtin_amdgcn_exp2f(sm_m[c][q] - mmax);
        lsum += sm_l[c][q] * wgt;
        float4 o4 = *(const float4*)&sm_acc[c][q][dg * 4];
        num0 = fmaf(o4.x, wgt, num0);
        num1 = fmaf(o4.y, wgt, num1);
        num2 = fmaf(o4.z, wgt, num2);
        num3 = fmaf(o4.w, wgt, num3);
    }
    float inv = 1.f / lsum;
    if (q0 + q < S_ROWS) {
        u16x4 st;
        st[0] = f2b(num0 * inv); st[1] = f2b(num1 * inv);
        st[2] = f2b(num2 * inv); st[3] = f2b(num3 * inv);
        *(u16x4*)(obb + (size_t)(q0 + q) * DIM + h * DH + dg * 4) = st;
    }
}

// ---------------------------------------------------------------------------
extern "C" void kernel_launch(void* const* d_in, const int* in_sizes, int n_in,
                              void* d_out, int out_size, void* d_ws, size_t ws_size,
                              hipStream_t stream)
{
    const float* pos   = (const float*)d_in[0];
    const float* scale = (const float*)d_in[1];
    const float* press = (const float*)d_in[2];
    const float* temp  = (const float*)d_in[3];
    const float* e_w0  = (const float*)d_in[4];
    const float* e_b0  = (const float*)d_in[5];
    const float* e_w1  = (const float*)d_in[6];
    const float* e_b1  = (const float*)d_in[7];
    const float* e_w2  = (const float*)d_in[8];
    const float* e_b2  = (const float*)d_in[9];
    const float* Wq    = (const float*)d_in[10];
    const float* Wk    = (const float*)d_in[11];
    const float* bk    = (const float*)d_in[12];
    const float* Wv    = (const float*)d_in[13];
    const float* Wo    = (const float*)d_in[14];
    const float* bo    = (const float*)d_in[15];
    const float* mw0   = (const float*)d_in[16];
    const float* mb0   = (const float*)d_in[17];
    const float* mw1   = (const float*)d_in[18];
    const float* mb1   = (const float*)d_in[19];
    const float* mw2   = (const float*)d_in[20];
    const float* mb2   = (const float*)d_in[21];
    const float* a_w0  = (const float*)d_in[22];
    const float* a_b0  = (const float*)d_in[23];
    const float* a_w1  = (const float*)d_in[24];
    const float* a_b1  = (const float*)d_in[25];
    const float* a_w2  = (const float*)d_in[26];
    const float* a_b2  = (const float*)d_in[27];
    float* out = (float*)d_out;

    const size_t WB_U16 = (size_t)EW0P_N + W_MAIN;   // 3990016

    float* ws = (float*)d_ws;
    size_t off = 0;
    float* hbuf = ws + off; off += 2048 * 256;             // f32 residual stream
    unsigned short* wbp   = (unsigned short*)(ws + off); off += WB_U16 / 2;
    unsigned short* cond  = (unsigned short*)(ws + off); off += 2048 * 64 / 2;
    unsigned short* obb   = (unsigned short*)(ws + off); off += 2048 * 256 / 2;
    unsigned short* qbh   = (unsigned short*)(ws + off); off += NHEADS * 2048 * 32 / 2;
    unsigned short* kbh   = (unsigned short*)(ws + off); off += NHEADS * 2048 * 32 / 2;
    unsigned short* vbT   = (unsigned short*)(ws + off); off += NHEADS * 2048 * 32 / 2;
    (void)ws_size;

    hipLaunchKernelGGL(setup_kernel, dim3(1024), dim3(256), 0, stream,
                       pos, scale, press, temp, e_w0,
                       e_w1, e_w2, Wq, Wk, Wv, Wo, mw0, mw1, mw2,
                       a_w0, a_w1, a_w2, wbp, cond, out);

    auto chain = [&](int mode) {
        hipLaunchKernelGGL(chain_kernel, dim3(256), dim3(512), 0, stream,
                           mode, wbp, cond, obb, hbuf, qbh, kbh, vbT,
                           e_b0, e_b1, e_b2, bo, mb0, mb1, mb2, bk,
                           a_b0, a_b1, a_b2, pos, out);
    };

    chain(-1);                                 // emb chain + qkv layer 0
    for (int l = 0; l < 4; l++) {
        hipLaunchKernelGGL(attn_mfma, dim3(64, NHEADS), dim3(256), 0, stream,
                           qbh, kbh, vbT, obb);
        chain(l);                              // Wo+MLP (+qkv next | +aff+spline)
    }
}

// Round 7
// 338.874 us; speedup vs baseline: 6.2409x; 1.2093x over previous
//
#include <hip/hip_runtime.h>
#include <math.h>

#define S_ROWS 2047
#define DIM 256
#define HID 512
#define NHEADS 8
#define DH 32
#define NBINS 16
#define AFF_OUT 49

typedef short bf16x8 __attribute__((ext_vector_type(8)));
typedef float f32x4 __attribute__((ext_vector_type(4)));
typedef float f32x16 __attribute__((ext_vector_type(16)));
typedef unsigned short u16x8 __attribute__((ext_vector_type(8)));
typedef unsigned short u16x4 __attribute__((ext_vector_type(4)));

__device__ inline unsigned short f2b(float f) {
    unsigned int u = __float_as_uint(f);
    u += 0x7FFFu + ((u >> 16) & 1u);      // round-to-nearest-even
    return (unsigned short)(u >> 16);
}

// ---------------------------------------------------------------------------
// Fused setup (verified): weight f32->bf16 conversion (+ew0 zero-pad to K=64),
// circular-feature embedding, pos copy + out[6144]=0.
// ---------------------------------------------------------------------------
#define W_MAIN 3957248
#define EW0P_N 32768
#define P0 (W_MAIN / 4)
#define P1 (P0 + EW0P_N / 4)
#define P2 (P1 + 2048 * 64 / 4)
#define P3 (P2 + 1537)
__global__ __launch_bounds__(256) void setup_kernel(
    const float* __restrict__ pos, const float* __restrict__ scale,
    const float* __restrict__ press, const float* __restrict__ temp,
    const float* __restrict__ e_w0, const float* __restrict__ p0,
    const float* __restrict__ p1, const float* __restrict__ p2,
    const float* __restrict__ p3, const float* __restrict__ p4,
    const float* __restrict__ p5, const float* __restrict__ p6,
    const float* __restrict__ p7, const float* __restrict__ p8,
    const float* __restrict__ p9, const float* __restrict__ p10,
    const float* __restrict__ p11, unsigned short* __restrict__ dst,
    unsigned short* __restrict__ cond, float* __restrict__ out)
{
    const int offs[13] = {0, 262144, 393216, 655360, 917504, 1179648, 1441792,
                          1966080, 3014656, 3538944, 3670016, 3932160, 3957248};
    const float* srcs[12] = {p0,p1,p2,p3,p4,p5,p6,p7,p8,p9,p10,p11};
    for (int i4 = blockIdx.x * blockDim.x + threadIdx.x; i4 < P3;
         i4 += gridDim.x * blockDim.x) {
        if (i4 < P0) {
            int e = i4 * 4;
            int s = 0;
            #pragma unroll
            for (int j = 1; j < 12; j++) s += (e >= offs[j]);
            const float4 v = *(const float4*)(srcs[s] + (e - offs[s]));
            u16x4 o;
            o[0] = f2b(v.x); o[1] = f2b(v.y); o[2] = f2b(v.z); o[3] = f2b(v.w);
            *(u16x4*)(dst + EW0P_N + e) = o;
        } else if (i4 < P1) {
            int e = (i4 - P0) * 4;
            u16x4 o;
            #pragma unroll
            for (int r = 0; r < 4; r++) {
                int ee = e + r;
                int row = ee >> 6, col = ee & 63;
                o[r] = (col < 35) ? f2b(e_w0[row * 35 + col]) : (unsigned short)0;
            }
            *(u16x4*)(dst + e) = o;
        } else if (i4 < P2) {
            int e = (i4 - P1) * 4;
            int row = e >> 6;
            u16x4 o;
            #pragma unroll
            for (int r = 0; r < 4; r++) {
                int c = (e + r) & 63;
                float v = 0.f;
                if (row < S_ROWS) {
                    if (c < 32) {
                        int coord = c >> 4;
                        int w = c & 15;
                        float x = pos[(row + 1) * 3 + coord];
                        float f = 6.283185307179586f * (float)((w & 7) + 1);
                        float ang = x * f;
                        v = (w < 8) ? cosf(ang) : sinf(ang);
                    } else if (c == 32) v = scale[0];
                    else if (c == 33) v = temp[0];
                    else if (c == 34) v = press[0];
                }
                o[r] = f2b(v);
            }
            *(u16x4*)(cond + e) = o;
        } else {
            int e = (i4 - P2) * 4;
            #pragma unroll
            for (int r = 0; r < 4; r++) {
                int ee = e + r;
                if (ee < 6144) out[ee] = pos[ee];
                else if (ee == 6144) out[ee] = 0.f;
            }
        }
    }
}

// ---------------------------------------------------------------------------
// bf16 MFMA GEMM, 32x32 tile, KSTEP=64 (round-4 verbatim; used for K=64 only).
// ---------------------------------------------------------------------------
#define LDK 72
__global__ __launch_bounds__(256, 4) void gemm_bf16_64(
    const unsigned short* __restrict__ Ab, const unsigned short* __restrict__ W,
    const float* __restrict__ bias, const float* resF,
    float* Cf, unsigned short* Cb, int M, int K, int relu)
{
    __shared__ unsigned short As[32][LDK];
    __shared__ unsigned short Bs[32][LDK];
    int tid = threadIdx.x;
    int wave = tid >> 6, lane = tid & 63;
    int quad = lane >> 4, l16 = lane & 15;
    int rowf = (wave & 1) << 4, colf = (wave >> 1) << 4;
    int row0 = blockIdx.y << 5, col0 = blockIdx.x << 5;
    int srow = tid >> 3, scol = (tid & 7) << 3;

    f32x4 acc = {0.f, 0.f, 0.f, 0.f};

    const u16x8* ap = (const u16x8*)(Ab + (size_t)(row0 + srow) * K + scol);
    const u16x8* wp = (const u16x8*)(W + (size_t)(col0 + srow) * K + scol);
    u16x8 a0 = ap[0];
    u16x8 b0 = wp[0];

    for (int k0 = 0; k0 < K; k0 += 64) {
        *(u16x8*)&As[srow][scol] = a0;
        *(u16x8*)&Bs[srow][scol] = b0;
        __syncthreads();
        if (k0 + 64 < K) {
            ap += 8; wp += 8;
            a0 = ap[0]; b0 = wp[0];
        }
        #pragma unroll
        for (int kt = 0; kt < 64; kt += 32) {
            bf16x8 af = *(bf16x8*)&As[rowf + l16][kt + (quad << 3)];
            bf16x8 bf = *(bf16x8*)&Bs[colf + l16][kt + (quad << 3)];
            acc = __builtin_amdgcn_mfma_f32_16x16x32_bf16(af, bf, acc, 0, 0, 0);
        }
        __syncthreads();
    }
    int col = col0 + colf + l16;
    if (col < M) {
        float bv = bias ? bias[col] : 0.f;
        #pragma unroll
        for (int r = 0; r < 4; r++) {
            int row = row0 + rowf + (quad << 2) + r;
            if (row >= S_ROWS) continue;
            float v = acc[r] + bv;
            if (resF) v += resF[(size_t)row * M + col];
            if (relu) v = fmaxf(v, 0.f);
            if (Cf) Cf[(size_t)row * M + col] = v;
            if (Cb) Cb[(size_t)row * M + col] = f2b(v);
        }
    }
}

// ---------------------------------------------------------------------------
// bf16 MFMA GEMM, 32x32 tile, KSTEP=128: half the barrier rounds of the
// KSTEP=64 version (mlp2: 16 -> 8), 4x u16x8 prefetch in flight. Same
// fragment math and epilogue (verified). Requires K % 128 == 0.
// ---------------------------------------------------------------------------
#define LDW 136
__global__ __launch_bounds__(256, 4) void gemm_bf16_128(
    const unsigned short* __restrict__ Ab, const unsigned short* __restrict__ W,
    const float* __restrict__ bias, const float* resF,
    float* Cf, unsigned short* Cb, int M, int K, int relu)
{
    __shared__ unsigned short As[32][LDW];
    __shared__ unsigned short Bs[32][LDW];
    int tid = threadIdx.x;
    int wave = tid >> 6, lane = tid & 63;
    int quad = lane >> 4, l16 = lane & 15;
    int rowf = (wave & 1) << 4, colf = (wave >> 1) << 4;
    int row0 = blockIdx.y << 5, col0 = blockIdx.x << 5;
    int srow = tid >> 3, scol = (tid & 7) << 4;      // 32 rows x 128 k stage

    f32x4 acc = {0.f, 0.f, 0.f, 0.f};

    const u16x8* ap = (const u16x8*)(Ab + (size_t)(row0 + srow) * K + scol);
    const u16x8* wp = (const u16x8*)(W + (size_t)(col0 + srow) * K + scol);
    u16x8 a0 = ap[0], a1 = ap[1];
    u16x8 b0 = wp[0], b1 = wp[1];

    for (int k0 = 0; k0 < K; k0 += 128) {
        *(u16x8*)&As[srow][scol]     = a0;
        *(u16x8*)&As[srow][scol + 8] = a1;
        *(u16x8*)&Bs[srow][scol]     = b0;
        *(u16x8*)&Bs[srow][scol + 8] = b1;
        __syncthreads();
        if (k0 + 128 < K) {              // prefetch next tile (stays in flight)
            ap += 16; wp += 16;
            a0 = ap[0]; a1 = ap[1];
            b0 = wp[0]; b1 = wp[1];
        }
        #pragma unroll
        for (int kt = 0; kt < 128; kt += 32) {
            bf16x8 af = *(bf16x8*)&As[rowf + l16][kt + (quad << 3)];
            bf16x8 bf = *(bf16x8*)&Bs[colf + l16][kt + (quad << 3)];
            acc = __builtin_amdgcn_mfma_f32_16x16x32_bf16(af, bf, acc, 0, 0, 0);
        }
        __syncthreads();
    }
    int col = col0 + colf + l16;
    if (col < M) {
        float bv = bias ? bias[col] : 0.f;
        #pragma unroll
        for (int r = 0; r < 4; r++) {
            int row = row0 + rowf + (quad << 2) + r;
            if (row >= S_ROWS) continue;
            float v = acc[r] + bv;
            if (resF) v += resF[(size_t)row * M + col];
            if (relu) v = fmaxf(v, 0.f);
            if (Cf) Cf[(size_t)row * M + col] = v;
            if (Cb) Cb[(size_t)row * M + col] = f2b(v);
        }
    }
}

// ---------------------------------------------------------------------------
// Fused QKV GEMM (32x32 tile, KSTEP=128, K=256) -> attention-native layouts
// (verified epilogue). Grid (24, 64) = 1536 blocks = 6/CU.
// ---------------------------------------------------------------------------
__global__ __launch_bounds__(256, 4) void gemm_qkv(
    const unsigned short* __restrict__ Ab, const unsigned short* __restrict__ Wq,
    const unsigned short* __restrict__ Wk, const unsigned short* __restrict__ Wv,
    const float* __restrict__ bk,
    unsigned short* __restrict__ qbh, unsigned short* __restrict__ kbh,
    unsigned short* __restrict__ vbT)
{
    __shared__ unsigned short As[32][LDW];
    __shared__ unsigned short Bs[32][LDW];
    const int N = S_ROWS, K = 256;
    int tid = threadIdx.x;
    int wave = tid >> 6, lane = tid & 63;
    int quad = lane >> 4, l16 = lane & 15;
    int rowf = (wave & 1) << 4, colf = (wave >> 1) << 4;
    int row0 = blockIdx.y << 5, col0 = blockIdx.x << 5;
    int mode = col0 >> 8;                 // 0=q 1=k 2=v
    int wcol0 = col0 & 255;
    const unsigned short* W = (mode == 0) ? Wq : (mode == 1) ? Wk : Wv;
    int srow = tid >> 3, scol = (tid & 7) << 4;

    f32x4 acc = {0.f, 0.f, 0.f, 0.f};

    const u16x8* ap = (const u16x8*)(Ab + (size_t)(row0 + srow) * K + scol);
    const u16x8* wp = (const u16x8*)(W + (size_t)(wcol0 + srow) * K + scol);
    u16x8 a0 = ap[0], a1 = ap[1];
    u16x8 b0 = wp[0], b1 = wp[1];

    for (int k0 = 0; k0 < K; k0 += 128) {
        *(u16x8*)&As[srow][scol]     = a0;
        *(u16x8*)&As[srow][scol + 8] = a1;
        *(u16x8*)&Bs[srow][scol]     = b0;
        *(u16x8*)&Bs[srow][scol + 8] = b1;
        __syncthreads();
        if (k0 + 128 < K) {
            ap += 16; wp += 16;
            a0 = ap[0]; a1 = ap[1];
            b0 = wp[0]; b1 = wp[1];
        }
        #pragma unroll
        for (int kt = 0; kt < 128; kt += 32) {
            bf16x8 af = *(bf16x8*)&As[rowf + l16][kt + (quad << 3)];
            bf16x8 bf = *(bf16x8*)&Bs[colf + l16][kt + (quad << 3)];
            acc = __builtin_amdgcn_mfma_f32_16x16x32_bf16(af, bf, acc, 0, 0, 0);
        }
        __syncthreads();
    }
    int colr = wcol0 + colf + l16;        // 0..255
    int hh = colr >> 5, d = colr & 31;
    int rbase = row0 + rowf + (quad << 2);
    if (mode == 2) {
        unsigned short* dst = vbT + ((size_t)hh * 32 + d) * 2048 + rbase;
        if (rbase + 3 < N) {
            u16x4 o;
            #pragma unroll
            for (int r = 0; r < 4; r++) o[r] = f2b(acc[r]);
            *(u16x4*)dst = o;
        } else {
            #pragma unroll
            for (int r = 0; r < 4; r++)
                if (rbase + r < N) dst[r] = f2b(acc[r]);
        }
    } else {
        float bias = (mode == 1) ? bk[colr] : 0.f;
        unsigned short* dst = ((mode == 0) ? qbh : kbh) + (size_t)hh * 2048 * 32 + d;
        #pragma unroll
        for (int r = 0; r < 4; r++) {
            int row = rbase + r;
            if (row < N) {
                float v = acc[r] + bias;
                if (mode == 0) v *= 0.25506362f;
                dst[(size_t)row * 32] = f2b(v);
            }
        }
    }
}

// ---------------------------------------------------------------------------
// MFMA flash attention, 8-wave split-K-8 (was 4-wave split-K-4): halves the
// serial per-wave K-loop (16 -> 8 iters) and doubles waves/CU (8 -> 16).
// Wave math verbatim from the verified kernel; combine extended to 8 chunks.
// Grid (64, 8) = 512 blocks x 512 threads = 2 blocks/CU.
// ---------------------------------------------------------------------------
__global__ __launch_bounds__(512, 2) void attn_mfma(
    const unsigned short* __restrict__ qbh,
    const unsigned short* __restrict__ kbh,
    const unsigned short* __restrict__ vbT,
    unsigned short* __restrict__ obb)
{
    int tid = threadIdx.x;
    int w = tid >> 6;                     // wave = K-chunk (0..7)
    int lane = tid & 63;
    int l31 = lane & 31, hf = lane >> 5;
    int q0 = blockIdx.x << 5;
    int h = blockIdx.y;
    int kstart = w * 256;
    int kend = min(kstart + 256, S_ROWS);

    const unsigned short* qp = qbh + ((size_t)h * 2048 + (q0 + l31)) * 32 + hf * 8;
    bf16x8 qf0 = *(const bf16x8*)(qp);
    bf16x8 qf1 = *(const bf16x8*)(qp + 16);

    const unsigned short* kb_h = kbh + (size_t)h * 2048 * 32;
    const unsigned short* vb_h = vbT + ((size_t)h * 32 + l31) * 2048;

    f32x16 acc = {};
    float m = -1e30f, l = 0.f;

    for (int key0 = kstart; key0 < kend; key0 += 32) {
        const unsigned short* kp = kb_h + (size_t)(key0 + l31) * 32 + hf * 8;
        bf16x8 kf0 = *(const bf16x8*)(kp);
        bf16x8 kf1 = *(const bf16x8*)(kp + 16);
        bf16x8 vf0 = *(const bf16x8*)(vb_h + key0 + hf * 8);
        bf16x8 vf1 = *(const bf16x8*)(vb_h + key0 + 16 + hf * 8);

        f32x16 sc = {};
        sc = __builtin_amdgcn_mfma_f32_32x32x16_bf16(kf0, qf0, sc, 0, 0, 0);
        sc = __builtin_amdgcn_mfma_f32_32x32x16_bf16(kf1, qf1, sc, 0, 0, 0);

        if (key0 + 32 > kend) {
            #pragma unroll
            for (int r = 0; r < 16; r++) {
                int kr = key0 + (r & 3) + 8 * (r >> 2) + 4 * hf;
                if (kr >= kend) sc[r] = -1e30f;
            }
        }
        float tmax = sc[0];
        #pragma unroll
        for (int r = 1; r < 16; r++) tmax = fmaxf(tmax, sc[r]);
        tmax = fmaxf(tmax, __shfl_xor(tmax, 32, 64));
        float mnew = fmaxf(m, tmax);
        float corr = __builtin_amdgcn_exp2f(m - mnew);
        m = mnew;
        float p[16];
        float ls = 0.f;
        #pragma unroll
        for (int r = 0; r < 16; r++) {
            p[r] = __builtin_amdgcn_exp2f(sc[r] - mnew);
            ls += p[r];
        }
        ls += __shfl_xor(ls, 32, 64);
        l = l * corr + ls;
        if (__ballot(corr != 1.0f)) {
            #pragma unroll
            for (int r = 0; r < 16; r++) acc[r] *= corr;
        }
        unsigned int pk[8];
        #pragma unroll
        for (int i = 0; i < 8; i++)
            pk[i] = __builtin_amdgcn_perm(__float_as_uint(p[2*i+1]),
                                          __float_as_uint(p[2*i]), 0x07060302u);
        unsigned int x[8];
        #pragma unroll
        for (int i = 0; i < 8; i++)
            x[i] = (unsigned int)__shfl_xor((int)pk[i], 32, 64);
        union { unsigned int u[4]; bf16x8 v; } B1, B2;
        B1.u[0] = hf ? x[2]  : pk[0];
        B1.u[1] = hf ? x[3]  : pk[1];
        B1.u[2] = hf ? pk[2] : x[0];
        B1.u[3] = hf ? pk[3] : x[1];
        B2.u[0] = hf ? x[6]  : pk[4];
        B2.u[1] = hf ? x[7]  : pk[5];
        B2.u[2] = hf ? pk[6] : x[4];
        B2.u[3] = hf ? pk[7] : x[5];
        acc = __builtin_amdgcn_mfma_f32_32x32x16_bf16(vf0, B1.v, acc, 0, 0, 0);
        acc = __builtin_amdgcn_mfma_f32_32x32x16_bf16(vf1, B2.v, acc, 0, 0, 0);
    }

    // ---- in-block split-K-8 combine through LDS ----
    __shared__ float sm_m[8][32];
    __shared__ float sm_l[8][32];
    __shared__ float sm_acc[8][32][36];
    if (!hf) { sm_m[w][l31] = m; sm_l[w][l31] = l; }
    #pragma unroll
    for (int g = 0; g < 4; g++) {
        float4 o4;
        o4.x = acc[4*g]; o4.y = acc[4*g+1]; o4.z = acc[4*g+2]; o4.w = acc[4*g+3];
        *(float4*)&sm_acc[w][l31][8*g + 4*hf] = o4;
    }
    __syncthreads();

    if (tid < 256) {
        int q = tid & 31;
        int dg = tid >> 5;                // 0..7
        float mmax = -1e30f;
        #pragma unroll
        for (int c = 0; c < 8; c++) mmax = fmaxf(mmax, sm_m[c][q]);
        float lsum = 0.f;
        float num0 = 0.f, num1 = 0.f, num2 = 0.f, num3 = 0.f;
        #pragma unroll
        for (int c = 0; c < 8; c++) {
            float wgt = __builtin_amdgcn_exp2f(sm_m[c][q] - mmax);
            lsum += sm_l[c][q] * wgt;
            float4 o4 = *(const float4*)&sm_acc[c][q][dg * 4];
            num0 = fmaf(o4.x, wgt, num0);
            num1 = fmaf(o4.y, wgt, num1);
            num2 = fmaf(o4.z, wgt, num2);
            num3 = fmaf(o4.w, wgt, num3);
        }
        float inv = 1.f / lsum;
        if (q0 + q < S_ROWS) {
            u16x4 st;
            st[0] = f2b(num0 * inv); st[1] = f2b(num1 * inv);
            st[2] = f2b(num2 * inv); st[3] = f2b(num3 * inv);
            *(u16x4*)(obb + (size_t)(q0 + q) * DIM + h * DH + dg * 4) = st;
        }
    }
}

// ---------------------------------------------------------------------------
// RQS spline (verified), wave-level logdet reduce + atomicAdd.
// ---------------------------------------------------------------------------
__global__ __launch_bounds__(64) void spline_kernel(const float* __restrict__ pos,
    const float* __restrict__ params, float* __restrict__ out)
{
    int r = blockIdx.x * 64 + threadIdx.x;
    float ld = 0.f;
    if (r < S_ROWS) {
        const float* p = params + (size_t)r * AFF_OUT;
        float x = pos[(r + 1) * 3 + 2];
        float xc = fminf(fmaxf(x, 0.f), 1.f);

        float mw = -1e30f, mh = -1e30f;
        #pragma unroll
        for (int j = 0; j < NBINS; j++) {
            mw = fmaxf(mw, p[j]);
            mh = fmaxf(mh, p[NBINS + j]);
        }
        float sw = 0.f, sh = 0.f;
        #pragma unroll
        for (int j = 0; j < NBINS; j++) {
            sw += __expf(p[j] - mw);
            sh += __expf(p[NBINS + j] - mh);
        }
        const float span = 1.0f - NBINS * 1e-4f;
        float scw = span / sw, sch = span / sh;

        float cumw = 0.f, cumh = 0.f;
        float xk = 0.f, yk = 0.f, wk = 0.f, hk = 0.f;
        int k = 0;
        #pragma unroll
        for (int j = 0; j < NBINS; j++) {
            float wj = __expf(p[j] - mw) * scw + 1e-4f;
            float hj = __expf(p[NBINS + j] - mh) * sch + 1e-4f;
            if (xc >= cumw) { k = j; xk = cumw; yk = cumh; wk = wj; hk = hj; }
            cumw += wj; cumh += hj;
        }
        float offset = logf(expm1f(0.9999f));
        float t0 = p[2 * NBINS + k] + offset;
        float t1 = ((k == NBINS - 1) ? p[2 * NBINS] : p[2 * NBINS + k + 1]) + offset;
        float dk  = ((t0 > 15.f) ? t0 : log1pf(__expf(t0))) + 1e-4f;
        float dk1 = ((t1 > 15.f) ? t1 : log1pf(__expf(t1))) + 1e-4f;

        float sl = hk / wk;
        float z = (xc - xk) / wk;
        float z1 = 1.f - z;
        float den = sl + (dk1 + dk - 2.f * sl) * z * z1;
        float y = yk + hk * (sl * z * z + dk * z * z1) / den;
        float ldv = 2.f * logf(sl)
                  + logf(dk1 * z * z + 2.f * sl * z * z1 + dk * z1 * z1)
                  - 2.f * logf(den);
        bool inside = (x >= 0.f) && (x <= 1.f);
        y = inside ? y : x;
        ld = inside ? ldv : 0.f;
        out[(r + 1) * 3 + 2] = y;
    }
    #pragma unroll
    for (int st = 32; st > 0; st >>= 1) ld += __shfl_xor(ld, st, 64);
    if (threadIdx.x == 0) atomicAdd(&out[6144], ld);
}

// ---------------------------------------------------------------------------
extern "C" void kernel_launch(void* const* d_in, const int* in_sizes, int n_in,
                              void* d_out, int out_size, void* d_ws, size_t ws_size,
                              hipStream_t stream)
{
    const float* pos   = (const float*)d_in[0];
    const float* scale = (const float*)d_in[1];
    const float* press = (const float*)d_in[2];
    const float* temp  = (const float*)d_in[3];
    const float* e_w0  = (const float*)d_in[4];
    const float* e_b0  = (const float*)d_in[5];
    const float* e_w1  = (const float*)d_in[6];
    const float* e_b1  = (const float*)d_in[7];
    const float* e_w2  = (const float*)d_in[8];
    const float* e_b2  = (const float*)d_in[9];
    const float* Wq    = (const float*)d_in[10];
    const float* Wk    = (const float*)d_in[11];
    const float* bk    = (const float*)d_in[12];
    const float* Wv    = (const float*)d_in[13];
    const float* Wo    = (const float*)d_in[14];
    const float* bo    = (const float*)d_in[15];
    const float* mw0   = (const float*)d_in[16];
    const float* mb0   = (const float*)d_in[17];
    const float* mw1   = (const float*)d_in[18];
    const float* mb1   = (const float*)d_in[19];
    const float* mw2   = (const float*)d_in[20];
    const float* mb2   = (const float*)d_in[21];
    const float* a_w0  = (const float*)d_in[22];
    const float* a_b0  = (const float*)d_in[23];
    const float* a_w1  = (const float*)d_in[24];
    const float* a_b1  = (const float*)d_in[25];
    const float* a_w2  = (const float*)d_in[26];
    const float* a_b2  = (const float*)d_in[27];
    float* out = (float*)d_out;

    // bf16 weight region offsets (u16 elements): [ew0p | main segments]
    enum { OFF_EW0 = 0,
           OFF_EW1 = 32768 + 0,       OFF_EW2 = 32768 + 262144,
           OFF_WQ  = 32768 + 393216,  OFF_WK  = 32768 + 655360,
           OFF_WV  = 32768 + 917504,  OFF_WO  = 32768 + 1179648,
           OFF_MW0 = 32768 + 1441792, OFF_MW1 = 32768 + 1966080,
           OFF_MW2 = 32768 + 3014656, OFF_AW0 = 32768 + 3538944,
           OFF_AW1 = 32768 + 3670016, OFF_AW2 = 32768 + 3932160 };
    const size_t WB_U16 = (size_t)EW0P_N + W_MAIN;   // 3990016

    float* ws = (float*)d_ws;
    size_t off = 0;
    float* hbuf = ws + off; off += 2048 * 256;             // f32 residual stream
    float* pr   = ws + off; off += 2048 * 64;              // spline params f32
    unsigned short* wbp   = (unsigned short*)(ws + off); off += WB_U16 / 2;
    unsigned short* cond  = (unsigned short*)(ws + off); off += 2048 * 64 / 2;
    unsigned short* t1b   = (unsigned short*)(ws + off); off += 2048 * 512 / 2;
    unsigned short* t2b   = (unsigned short*)(ws + off); off += 2048 * 512 / 2;
    unsigned short* hb    = (unsigned short*)(ws + off); off += 2048 * 256 / 2;
    unsigned short* obb   = (unsigned short*)(ws + off); off += 2048 * 256 / 2;
    unsigned short* qbh   = (unsigned short*)(ws + off); off += NHEADS * 2048 * 32 / 2;
    unsigned short* kbh   = (unsigned short*)(ws + off); off += NHEADS * 2048 * 32 / 2;
    unsigned short* vbT   = (unsigned short*)(ws + off); off += NHEADS * 2048 * 32 / 2;
    (void)ws_size;

    hipLaunchKernelGGL(setup_kernel, dim3(1024), dim3(256), 0, stream,
                       pos, scale, press, temp, e_w0,
                       e_w1, e_w2, Wq, Wk, Wv, Wo, mw0, mw1, mw2,
                       a_w0, a_w1, a_w2, wbp, cond, out);

    auto gemm = [&](const unsigned short* A, const unsigned short* W,
                    const float* bias, const float* resF, float* Cf,
                    unsigned short* Cb, int M, int K, int relu) {
        dim3 grid((M + 31) / 32, 64);
        if (K % 128 == 0)
            hipLaunchKernelGGL(gemm_bf16_128, grid, dim3(256), 0, stream,
                               A, W, bias, resF, Cf, Cb, M, K, relu);
        else
            hipLaunchKernelGGL(gemm_bf16_64, grid, dim3(256), 0, stream,
                               A, W, bias, resF, Cf, Cb, M, K, relu);
    };

    // embedding MLP: 35(->64) -> 512 -> 512 -> 256
    gemm(cond, wbp + OFF_EW0, e_b0, nullptr, nullptr, t1b, 512, 64, 1);
    gemm(t1b,  wbp + OFF_EW1, e_b1, nullptr, nullptr, t2b, 512, 512, 1);
    gemm(t2b,  wbp + OFF_EW2, e_b2, nullptr, hbuf, hb, 256, 512, 0);

    for (int l = 0; l < 4; l++) {
        hipLaunchKernelGGL(gemm_qkv, dim3(24, 64), dim3(256), 0, stream,
                           hb, wbp + OFF_WQ + l * 65536, wbp + OFF_WK + l * 65536,
                           wbp + OFF_WV + l * 65536, bk + l * 256, qbh, kbh, vbT);
        hipLaunchKernelGGL(attn_mfma, dim3(64, NHEADS), dim3(512), 0, stream,
                           qbh, kbh, vbT, obb);
        gemm(obb, wbp + OFF_WO + l * 65536, bo + l * 256, hbuf, hbuf, hb, 256, 256, 0);
        gemm(hb,  wbp + OFF_MW0 + l * 131072, mb0 + l * 512, nullptr, nullptr, t1b, 512, 256, 1);
        gemm(t1b, wbp + OFF_MW1 + l * 262144, mb1 + l * 512, nullptr, nullptr, t2b, 512, 512, 1);
        gemm(t2b, wbp + OFF_MW2 + l * 131072, mb2 + l * 256, hbuf, hbuf, hb, 256, 512, 0);
    }

    // affine-param MLP: 256 -> 512 -> 512 -> 49
    gemm(hb,  wbp + OFF_AW0, a_b0, nullptr, nullptr, t1b, 512, 256, 1);
    gemm(t1b, wbp + OFF_AW1, a_b1, nullptr, nullptr, t2b, 512, 512, 1);
    gemm(t2b, wbp + OFF_AW2, a_b2, nullptr, pr, nullptr, AFF_OUT, 512, 0);

    hipLaunchKernelGGL(spline_kernel, dim3(32), dim3(64), 0, stream, pos, pr, out);
}